// Round 7
// baseline (378.617 us; speedup 1.0000x reference)
//
#include <hip/hip_runtime.h>

#define NN 50000
#define NE 800000
#define NF 128
#define NH 64
#define BN_EPS 1e-5f
#define NB 196       // ceil(NN/256) coarse buckets (256 nodes each)
#define EPB 4096     // edges per k_part block
#define CAP 5120     // per-bucket capacity in k_sub
#define NCOPY 16
#define SEG (NCOPY * 128)

typedef __bf16 bf16x8 __attribute__((ext_vector_type(8)));
typedef float f32x4 __attribute__((ext_vector_type(4)));
#define MFMA __builtin_amdgcn_mfma_f32_16x16x32_bf16

__device__ inline unsigned short bf_hi(float f) {
  unsigned u = __float_as_uint(f);
  unsigned r = u + 0x7FFFu + ((u >> 16) & 1u);
  return (unsigned short)(r >> 16);
}
__device__ inline float bf_to_f(unsigned short s) {
  return __uint_as_float(((unsigned)s) << 16);
}

union BF8 { bf16x8 v; unsigned short s[8]; };

// Build hi/lo bf16x8 fragments from 8 consecutive fp32.
__device__ inline void make_ab(const float* p, bool valid, bf16x8& hi, bf16x8& lo) {
  BF8 H, L;
  if (valid) {
    float4 f0 = *(const float4*)p;
    float4 f1 = *(const float4*)(p + 4);
    float ff[8] = {f0.x, f0.y, f0.z, f0.w, f1.x, f1.y, f1.z, f1.w};
#pragma unroll
    for (int e = 0; e < 8; ++e) {
      unsigned short h = bf_hi(ff[e]);
      H.s[e] = h;
      L.s[e] = bf_hi(ff[e] - bf_to_f(h));
    }
  } else {
#pragma unroll
    for (int e = 0; e < 8; ++e) { H.s[e] = 0; L.s[e] = 0; }
  }
  hi = H.v; lo = L.v;
}

template <int K>
__device__ inline void stage_w(const float* __restrict__ W,
                               unsigned short* __restrict__ wh,
                               unsigned short* __restrict__ wl) {
  int t = threadIdx.x;
#pragma unroll
  for (int i = 0; i < K * 64 / 256; ++i) {
    int idx = t + i * 256;
    int k = idx >> 6, c = idx & 63;
    float f = W[idx];
    unsigned short h = bf_hi(f);
    unsigned short l = bf_hi(f - bf_to_f(h));
    int off = ((k >> 5) * 4 + (c >> 4)) * 512 + (((k >> 3) & 3) * 16 + (c & 15)) * 8 + (k & 7);
    wh[off] = h;
    wl[off] = l;
  }
}

// ---------------- zero ----------------

__global__ void k_zero(int* __restrict__ chist, float* __restrict__ partials) {
  int i = blockIdx.x * 256 + threadIdx.x;
  if (i < NB) chist[i] = 0;
  if (i < 4 * SEG) partials[i] = 0.f;
}

// ---------------- coarse histogram (dst>>8) ----------------

__global__ __launch_bounds__(256) void k_hist(const int* __restrict__ dst,
                                              int* __restrict__ chist) {
  __shared__ int lh[NB];
  int t = threadIdx.x;
  for (int i = t; i < NB; i += 256) lh[i] = 0;
  __syncthreads();
  int e0 = blockIdx.x * EPB;
#pragma unroll
  for (int i = 0; i < EPB / 256; ++i) {
    int e = e0 + i * 256 + t;
    if (e < NE) atomicAdd(&lh[dst[e] >> 8], 1);
  }
  __syncthreads();
  for (int i = t; i < NB; i += 256)
    if (lh[i]) atomicAdd(&chist[i], lh[i]);
}

__global__ __launch_bounds__(256) void k_cscan(const int* __restrict__ chist,
                                               int* __restrict__ cbase,
                                               int* __restrict__ ccur) {
  __shared__ int ls[256];
  int t = threadIdx.x;
  int v = (t < NB) ? chist[t] : 0;
  ls[t] = v;
  __syncthreads();
  for (int off = 1; off < 256; off <<= 1) {
    int u = (t >= off) ? ls[t - off] : 0;
    __syncthreads();
    ls[t] += u;
    __syncthreads();
  }
  if (t < NB) { cbase[t] = ls[t] - v; ccur[t] = ls[t] - v; }
  if (t == 0) cbase[NB] = NE;
}

// -------- phase 1: partition packed records by coarse bucket --------

__global__ __launch_bounds__(256) void k_part(const int* __restrict__ src,
                                              const int* __restrict__ dst,
                                              int* __restrict__ ccur,
                                              int* __restrict__ pairs) {
  __shared__ int lh[NB];
  __shared__ int gb[NB];
  __shared__ int lc[NB];
  __shared__ int ls[256];
  __shared__ int lp[EPB];
  __shared__ int gx[EPB];
  int t = threadIdx.x;
  for (int i = t; i < NB; i += 256) lh[i] = 0;
  __syncthreads();
  int e0 = blockIdx.x * EPB;
  int nloc = NE - e0; if (nloc > EPB) nloc = EPB;
#pragma unroll
  for (int i = 0; i < EPB / 256; ++i) {
    int e = e0 + i * 256 + t;
    if (e < NE) atomicAdd(&lh[dst[e] >> 8], 1);
  }
  __syncthreads();
  int v = (t < NB) ? lh[t] : 0;
  ls[t] = v;
  __syncthreads();
  for (int off = 1; off < 256; off <<= 1) {
    int u = (t >= off) ? ls[t - off] : 0;
    __syncthreads();
    ls[t] += u;
    __syncthreads();
  }
  int lbase = ls[t] - v;
  int gbase = 0;
  if (t < NB && v > 0) gbase = atomicAdd(&ccur[t], v);
  if (t < NB) { lh[t] = lbase; gb[t] = gbase; lc[t] = 0; }
  __syncthreads();
#pragma unroll
  for (int i = 0; i < EPB / 256; ++i) {
    int e = e0 + i * 256 + t;
    if (e < NE) {
      int d = dst[e], s = src[e];
      int b = d >> 8;
      int lpos = lh[b] + atomicAdd(&lc[b], 1);
      lp[lpos] = ((d & 255) << 16) | s;
      gx[lpos] = gb[b] - lh[b];
    }
  }
  __syncthreads();
  for (int i = t; i < nloc; i += 256) pairs[gx[i] + i] = lp[i];
}

// ---------------- phase 2: exact sort within bucket ----------------

__global__ __launch_bounds__(256) void k_sub(const int* __restrict__ pairs,
                                             const int* __restrict__ cbase,
                                             int* __restrict__ rowptr,
                                             int* __restrict__ ebuf) {
  __shared__ int lh[256];
  __shared__ int lsc[256];
  __shared__ int lc2[256];
  __shared__ unsigned short ssrc[CAP];
  int t = threadIdx.x;
  int b = blockIdx.x;
  int beg = cbase[b], end = cbase[b + 1];
  int n = end - beg;
  lh[t] = 0;
  lc2[t] = 0;
  __syncthreads();
  for (int i = t; i < n; i += 256) atomicAdd(&lh[(pairs[beg + i] >> 16) & 255], 1);
  __syncthreads();
  int v = lh[t];
  lsc[t] = v;
  __syncthreads();
  for (int off = 1; off < 256; off <<= 1) {
    int u = (t >= off) ? lsc[t - off] : 0;
    __syncthreads();
    lsc[t] += u;
    __syncthreads();
  }
  int excl = lsc[t] - v;
  int node = b * 256 + t;
  if (node <= NN) rowptr[node] = beg + excl;
  for (int i = t; i < n; i += 256) {
    int p = pairs[beg + i];
    int ln = (p >> 16) & 255;
    int lpos = (lsc[ln] - lh[ln]) + atomicAdd(&lc2[ln], 1);
    if (lpos < CAP) ssrc[lpos] = (unsigned short)(p & 0xFFFF);
  }
  __syncthreads();
  for (int i = t; i < n; i += 256) ebuf[beg + i] = (int)ssrc[i];
}

// ---------------- input transform (MFMA): zb = bf16(x @ Wt + bt), + stats ----------------

__global__ __launch_bounds__(256) void k_in(const float* __restrict__ x,
                                            const float* __restrict__ Wt,
                                            const float* __restrict__ bt,
                                            unsigned short* __restrict__ zb,
                                            float* __restrict__ part_out) {
  __shared__ unsigned short wh[8192], wl[8192];  // 32 KB
  __shared__ float reds[16][64], redss[16][64];  // 8 KB
  int t = threadIdx.x;
  stage_w<NF>(Wt, wh, wl);
  int wv = t >> 6, lane = t & 63;
  int c15 = lane & 15, kg = lane >> 4;
  int n0 = blockIdx.x * 64 + wv * 16;
  int arow = n0 + c15;

  bf16x8 ah[4], al[4];
  const float* ap = x + (size_t)arow * NF + kg * 8;
#pragma unroll
  for (int ks = 0; ks < 4; ++ks) make_ab(ap + ks * 32, arow < NN, ah[ks], al[ks]);
  __syncthreads();

  const bf16x8* bh = (const bf16x8*)wh;
  const bf16x8* bl = (const bf16x8*)wl;
  float sAcc[4], ssAcc[4];
#pragma unroll
  for (int ct = 0; ct < 4; ++ct) {
    f32x4 acc = {0.f, 0.f, 0.f, 0.f};
#pragma unroll
    for (int ks = 0; ks < 4; ++ks) {
      bf16x8 wbh = bh[(ks * 4 + ct) * 64 + kg * 16 + c15];
      bf16x8 wbl = bl[(ks * 4 + ct) * 64 + kg * 16 + c15];
      acc = MFMA(al[ks], wbh, acc, 0, 0, 0);
      acc = MFMA(ah[ks], wbl, acc, 0, 0, 0);
      acc = MFMA(ah[ks], wbh, acc, 0, 0, 0);
    }
    float b = bt[ct * 16 + c15];
    float s = 0.f, ss = 0.f;
#pragma unroll
    for (int g = 0; g < 4; ++g) {
      int row = n0 + kg * 4 + g;
      float v = acc[g] + b;
      if (row < NN) {
        zb[(size_t)row * NH + ct * 16 + c15] = bf_hi(v);
        s += v;
        ss += v * v;
      }
    }
    sAcc[ct] = s;
    ssAcc[ct] = ss;
  }
#pragma unroll
  for (int ct = 0; ct < 4; ++ct) {
    reds[wv * 4 + kg][ct * 16 + c15] = sAcc[ct];
    redss[wv * 4 + kg][ct * 16 + c15] = ssAcc[ct];
  }
  __syncthreads();
  if (t < 64) {
    float s2 = 0.f, ss2 = 0.f;
#pragma unroll
    for (int i = 0; i < 16; ++i) { s2 += reds[i][t]; ss2 += redss[i][t]; }
    int cp = (blockIdx.x & (NCOPY - 1)) * 128;
    atomicAdd(&part_out[cp + t], s2);
    atomicAdd(&part_out[cp + 64 + t], ss2);
  }
}

// -------- fused layer: agg(BN-affine) + MLP + stats, all bf16 planes --------
// rb = bf16( relu( relu( BN(agg) @ W1 ) @ W2 ) ), stats of relu output -> part_out

__global__ __launch_bounds__(256) void k_fused(const unsigned short* __restrict__ zb,
                                               const int* __restrict__ rowptr,
                                               const int* __restrict__ ebuf,
                                               const float* __restrict__ part_in,
                                               const float* __restrict__ gamma,
                                               const float* __restrict__ beta,
                                               const float* __restrict__ W1,
                                               const float* __restrict__ W2,
                                               unsigned short* __restrict__ rb,
                                               float* __restrict__ part_out) {
  __shared__ unsigned short w1h[4096], w1l[4096], w2h[4096], w2l[4096];  // 32 KB
  __shared__ __align__(16) char uni[4][4608];  // per-wave: ms fp32 [16][68] / tls [2][16][72]
  __shared__ float sc[64], sh[64];
  int t = threadIdx.x;
  stage_w<NH>(W1, w1h, w1l);
  stage_w<NH>(W2, w2h, w2l);
  if (t < 64) {
    float s = 0.f, ss = 0.f;
#pragma unroll
    for (int c = 0; c < NCOPY; ++c) { s += part_in[c * 128 + t]; ss += part_in[c * 128 + 64 + t]; }
    float invn = 1.f / (float)NN;
    float mu = s * invn;
    float var = fmaxf(ss * invn - mu * mu, 0.f);
    float inv = rsqrtf(var + BN_EPS);
    float scale = gamma[t] * inv;
    sc[t] = scale;
    sh[t] = beta[t] - mu * scale;
  }
  __syncthreads();  // B1: W planes + sc/sh ready

  int wv = t >> 6, lane = t & 63;
  int c15 = lane & 15, kg = lane >> 4;
  int n0 = blockIdx.x * 64 + wv * 16;
  float* ms = (float*)uni[wv];  // [16][68]

  // ---- gather + BN affine into ms ----
  {
    int c = c15;        // channel group: channels 4c..4c+3
    int e = kg;         // edge slot 0..3
    for (int r = 0; r < 16; ++r) {
      int node = n0 + r;
      float a0 = 0.f, a1 = 0.f, a2 = 0.f, a3 = 0.f;
      int beg = 0, end = 0;
      if (node < NN) {
        beg = rowptr[node];
        end = rowptr[node + 1];
        if (e == 0) {
          uint2 u = *(const uint2*)(zb + (size_t)node * NH + c * 4);
          a0 += bf_to_f((unsigned short)(u.x & 0xFFFFu));
          a1 += bf_to_f((unsigned short)(u.x >> 16));
          a2 += bf_to_f((unsigned short)(u.y & 0xFFFFu));
          a3 += bf_to_f((unsigned short)(u.y >> 16));
        }
        for (int j = beg + e; j < end; j += 4) {
          int s = ebuf[j];
          uint2 u = *(const uint2*)(zb + (size_t)s * NH + c * 4);
          a0 += bf_to_f((unsigned short)(u.x & 0xFFFFu));
          a1 += bf_to_f((unsigned short)(u.x >> 16));
          a2 += bf_to_f((unsigned short)(u.y & 0xFFFFu));
          a3 += bf_to_f((unsigned short)(u.y >> 16));
        }
      }
      a0 += __shfl_xor(a0, 16); a0 += __shfl_xor(a0, 32);
      a1 += __shfl_xor(a1, 16); a1 += __shfl_xor(a1, 32);
      a2 += __shfl_xor(a2, 16); a2 += __shfl_xor(a2, 32);
      a3 += __shfl_xor(a3, 16); a3 += __shfl_xor(a3, 32);
      if (e == 0) {
        int c0 = 4 * c;
        float4 o = make_float4(0.f, 0.f, 0.f, 0.f);
        if (node < NN) {
          float deg1 = (float)(end - beg + 1);
          o.x = sc[c0 + 0] * a0 + deg1 * sh[c0 + 0];
          o.y = sc[c0 + 1] * a1 + deg1 * sh[c0 + 1];
          o.z = sc[c0 + 2] * a2 + deg1 * sh[c0 + 2];
          o.w = sc[c0 + 3] * a3 + deg1 * sh[c0 + 3];
        }
        *(float4*)&ms[r * 68 + c0] = o;
      }
    }
  }

  // ---- A1 fragments from ms (own-wave tile) ----
  bf16x8 ah[2], al[2];
  {
    const float* mp = &ms[c15 * 68];
    make_ab(mp + kg * 8, true, ah[0], al[0]);
    make_ab(mp + 32 + kg * 8, true, ah[1], al[1]);
  }
  __syncthreads();  // B2: ms reads done everywhere (uni about to be overwritten)

  // ---- GEMM1: t = relu(m @ W1) ----
  const bf16x8* b1h = (const bf16x8*)w1h;
  const bf16x8* b1l = (const bf16x8*)w1l;
  float tv[4][4];
#pragma unroll
  for (int ct = 0; ct < 4; ++ct) {
    f32x4 acc = {0.f, 0.f, 0.f, 0.f};
#pragma unroll
    for (int ks = 0; ks < 2; ++ks) {
      bf16x8 wbh = b1h[(ks * 4 + ct) * 64 + kg * 16 + c15];
      bf16x8 wbl = b1l[(ks * 4 + ct) * 64 + kg * 16 + c15];
      acc = MFMA(al[ks], wbh, acc, 0, 0, 0);
      acc = MFMA(ah[ks], wbl, acc, 0, 0, 0);
      acc = MFMA(ah[ks], wbh, acc, 0, 0, 0);
    }
#pragma unroll
    for (int g = 0; g < 4; ++g) tv[ct][g] = fmaxf(acc[g], 0.f);
  }
  // write t (hi/lo) into uni (tls layout [2][16][72])
  {
    unsigned short* tl0 = (unsigned short*)uni[wv];
    unsigned short* tl1 = tl0 + 16 * 72;
#pragma unroll
    for (int ct = 0; ct < 4; ++ct)
#pragma unroll
      for (int g = 0; g < 4; ++g) {
        int rr = kg * 4 + g, cc = ct * 16 + c15;
        unsigned short h = bf_hi(tv[ct][g]);
        tl0[rr * 72 + cc] = h;
        tl1[rr * 72 + cc] = bf_hi(tv[ct][g] - bf_to_f(h));
      }
  }
  __syncthreads();  // B3: all GEMM1 w1-reads done (w1 region about to host reds)

  // ---- GEMM2: r = relu(t @ W2) ----
  bf16x8 a2h[2], a2l[2];
  {
    const unsigned short* tl0 = (const unsigned short*)uni[wv];
    const unsigned short* tl1 = tl0 + 16 * 72;
#pragma unroll
    for (int ks = 0; ks < 2; ++ks) {
      a2h[ks] = *(const bf16x8*)&tl0[c15 * 72 + ks * 32 + kg * 8];
      a2l[ks] = *(const bf16x8*)&tl1[c15 * 72 + ks * 32 + kg * 8];
    }
  }
  const bf16x8* b2h = (const bf16x8*)w2h;
  const bf16x8* b2l = (const bf16x8*)w2l;
  float sAcc[4], ssAcc[4];
#pragma unroll
  for (int ct = 0; ct < 4; ++ct) {
    f32x4 acc = {0.f, 0.f, 0.f, 0.f};
#pragma unroll
    for (int ks = 0; ks < 2; ++ks) {
      bf16x8 wbh = b2h[(ks * 4 + ct) * 64 + kg * 16 + c15];
      bf16x8 wbl = b2l[(ks * 4 + ct) * 64 + kg * 16 + c15];
      acc = MFMA(a2l[ks], wbh, acc, 0, 0, 0);
      acc = MFMA(a2h[ks], wbl, acc, 0, 0, 0);
      acc = MFMA(a2h[ks], wbh, acc, 0, 0, 0);
    }
    float s = 0.f, ss = 0.f;
#pragma unroll
    for (int g = 0; g < 4; ++g) {
      float v = fmaxf(acc[g], 0.f);
      int row = n0 + kg * 4 + g;
      if (row < NN) rb[(size_t)row * NH + ct * 16 + c15] = bf_hi(v);
      s += v;   // OOB rows produce exactly 0
      ss += v * v;
    }
    sAcc[ct] = s;
    ssAcc[ct] = ss;
  }
  // reds/redss aliased onto dead w1 planes
  float* reds = (float*)w1h;   // [16][64]
  float* redss = (float*)w1l;  // [16][64]
#pragma unroll
  for (int ct = 0; ct < 4; ++ct) {
    reds[(wv * 4 + kg) * 64 + ct * 16 + c15] = sAcc[ct];
    redss[(wv * 4 + kg) * 64 + ct * 16 + c15] = ssAcc[ct];
  }
  __syncthreads();  // B4
  if (t < 64) {
    float s2 = 0.f, ss2 = 0.f;
#pragma unroll
    for (int i = 0; i < 16; ++i) { s2 += reds[i * 64 + t]; ss2 += redss[i * 64 + t]; }
    int cp = (blockIdx.x & (NCOPY - 1)) * 128;
    atomicAdd(&part_out[cp + t], s2);
    atomicAdd(&part_out[cp + 64 + t], ss2);
  }
}

// ---------------- final BN apply (bf16 in, fp32 out) ----------------

__global__ __launch_bounds__(256) void k_apply(const unsigned short* __restrict__ rb,
                                               const float* __restrict__ part,
                                               const float* __restrict__ gamma,
                                               const float* __restrict__ beta,
                                               float* __restrict__ out) {
  __shared__ float sc[64], sh[64];
  int t = threadIdx.x;
  if (t < 64) {
    float s = 0.f, ss = 0.f;
#pragma unroll
    for (int c = 0; c < NCOPY; ++c) { s += part[c * 128 + t]; ss += part[c * 128 + 64 + t]; }
    float invn = 1.f / (float)NN;
    float mu = s * invn;
    float var = fmaxf(ss * invn - mu * mu, 0.f);
    float inv = rsqrtf(var + BN_EPS);
    float scale = gamma[t] * inv;
    sc[t] = scale;
    sh[t] = beta[t] - mu * scale;
  }
  __syncthreads();
  int i = blockIdx.x * 256 + t;  // 4-channel group index
  if (i < NN * (NH / 4)) {
    int c0 = (i * 4) & 63;
    uint2 u = ((const uint2*)rb)[i];
    float4 o;
    o.x = bf_to_f((unsigned short)(u.x & 0xFFFFu)) * sc[c0 + 0] + sh[c0 + 0];
    o.y = bf_to_f((unsigned short)(u.x >> 16)) * sc[c0 + 1] + sh[c0 + 1];
    o.z = bf_to_f((unsigned short)(u.y & 0xFFFFu)) * sc[c0 + 2] + sh[c0 + 2];
    o.w = bf_to_f((unsigned short)(u.y >> 16)) * sc[c0 + 3] + sh[c0 + 3];
    ((float4*)out)[i] = o;
  }
}

// ---------------- launch ----------------

extern "C" void kernel_launch(void* const* d_in, const int* in_sizes, int n_in,
                              void* d_out, int out_size, void* d_ws, size_t ws_size,
                              hipStream_t stream) {
  (void)in_sizes; (void)n_in; (void)out_size; (void)ws_size;
  const float* x      = (const float*)d_in[0];
  const int*   ei     = (const int*)d_in[1];
  const float* Wt     = (const float*)d_in[2];
  const float* bt     = (const float*)d_in[3];
  const float* gt     = (const float*)d_in[4];
  const float* bet    = (const float*)d_in[5];
  const float* Ws1    = (const float*)d_in[6];
  const float* Ws2    = (const float*)d_in[7];
  const float* gammas = (const float*)d_in[8];
  const float* betas  = (const float*)d_in[9];

  const int* esrc = ei;
  const int* edst = ei + NE;

  int*            pairs    = (int*)d_ws;                 // NE (dead after k_sub)
  int*            ebuf     = pairs + NE;                 // NE
  int*            rowptr   = ebuf + NE;                  // NN+1
  int*            chist    = rowptr + NN + 1;            // NB
  int*            cbase    = chist + NB;                 // NB+1
  int*            ccur     = cbase + NB + 1;             // NB
  float*          partials = (float*)(ccur + NB);        // 4 x SEG
  unsigned short* bfA      = (unsigned short*)(partials + 4 * SEG);  // NN*NH
  unsigned short* bfB      = bfA + (size_t)NN * NH;                  // NN*NH

  const int GB = (NN + 63) / 64;  // 782

  // CSR build
  k_zero<<<(4 * SEG + 255) / 256, 256, 0, stream>>>(chist, partials);
  k_hist<<<(NE + EPB - 1) / EPB, 256, 0, stream>>>(edst, chist);
  k_cscan<<<1, 256, 0, stream>>>(chist, cbase, ccur);
  k_part<<<(NE + EPB - 1) / EPB, 256, 0, stream>>>(esrc, edst, ccur, pairs);
  k_sub<<<NB, 256, 0, stream>>>(pairs, cbase, rowptr, ebuf);

  // input transform (bf16 plane + stats seg0)
  k_in<<<GB, 256, 0, stream>>>(x, Wt, bt, bfA, partials);

  // 3 fused layers
  k_fused<<<GB, 256, 0, stream>>>(bfA, rowptr, ebuf, partials, gt, bet,
                                  Ws1, Ws2, bfB, partials + SEG);
  k_fused<<<GB, 256, 0, stream>>>(bfB, rowptr, ebuf, partials + SEG, gammas, betas,
                                  Ws1 + NH * NH, Ws2 + NH * NH, bfA, partials + 2 * SEG);
  k_fused<<<GB, 256, 0, stream>>>(bfA, rowptr, ebuf, partials + 2 * SEG, gammas + NH,
                                  betas + NH, Ws1 + 2 * NH * NH, Ws2 + 2 * NH * NH, bfB,
                                  partials + 3 * SEG);

  // final BN apply -> d_out
  k_apply<<<(NN * (NH / 4) + 255) / 256, 256, 0, stream>>>(bfB, partials + 3 * SEG,
                                                           gammas + 2 * NH, betas + 2 * NH,
                                                           (float*)d_out);
}

// Round 8
// 199.885 us; speedup vs baseline: 1.8942x; 1.8942x over previous
//
#include <hip/hip_runtime.h>

#define NN 50000
#define NE 800000
#define NF 128
#define NH 64
#define BN_EPS 1e-5f
#define NB 196       // ceil(NN/256) coarse buckets (256 nodes each)
#define EPB 4096     // edges per k_part block
#define CAP 5120     // per-bucket capacity in k_sub
#define NCOPY 16
#define SEG (NCOPY * 128)

typedef __bf16 bf16x8 __attribute__((ext_vector_type(8)));
typedef float f32x4 __attribute__((ext_vector_type(4)));
#define MFMA __builtin_amdgcn_mfma_f32_16x16x32_bf16

__device__ inline unsigned short bf_hi(float f) {
  unsigned u = __float_as_uint(f);
  unsigned r = u + 0x7FFFu + ((u >> 16) & 1u);
  return (unsigned short)(r >> 16);
}
__device__ inline float bf_to_f(unsigned short s) {
  return __uint_as_float(((unsigned)s) << 16);
}
__device__ inline float bf_lo_f(unsigned u) {  // low bf16 of a uint
  return __uint_as_float(u << 16);
}
__device__ inline float bf_hi_f(unsigned u) {  // high bf16 of a uint
  return __uint_as_float(u & 0xFFFF0000u);
}

union BF8 { bf16x8 v; unsigned short s[8]; };

__device__ inline void make_ab(const float* p, bool valid, bf16x8& hi, bf16x8& lo) {
  BF8 H, L;
  if (valid) {
    float4 f0 = *(const float4*)p;
    float4 f1 = *(const float4*)(p + 4);
    float ff[8] = {f0.x, f0.y, f0.z, f0.w, f1.x, f1.y, f1.z, f1.w};
#pragma unroll
    for (int e = 0; e < 8; ++e) {
      unsigned short h = bf_hi(ff[e]);
      H.s[e] = h;
      L.s[e] = bf_hi(ff[e] - bf_to_f(h));
    }
  } else {
#pragma unroll
    for (int e = 0; e < 8; ++e) { H.s[e] = 0; L.s[e] = 0; }
  }
  hi = H.v; lo = L.v;
}

template <int K>
__device__ inline void stage_w(const float* __restrict__ W,
                               unsigned short* __restrict__ wh,
                               unsigned short* __restrict__ wl) {
  int t = threadIdx.x;
#pragma unroll
  for (int i = 0; i < K * 64 / 256; ++i) {
    int idx = t + i * 256;
    int k = idx >> 6, c = idx & 63;
    float f = W[idx];
    unsigned short h = bf_hi(f);
    unsigned short l = bf_hi(f - bf_to_f(h));
    int off = ((k >> 5) * 4 + (c >> 4)) * 512 + (((k >> 3) & 3) * 16 + (c & 15)) * 8 + (k & 7);
    wh[off] = h;
    wl[off] = l;
  }
}

// ---------------- zero ----------------

__global__ void k_zero(int* __restrict__ chist, float* __restrict__ partials) {
  int i = blockIdx.x * 256 + threadIdx.x;
  if (i < NB) chist[i] = 0;
  if (i < 4 * SEG) partials[i] = 0.f;
}

// ---------------- coarse histogram (dst>>8) ----------------

__global__ __launch_bounds__(256) void k_hist(const int* __restrict__ dst,
                                              int* __restrict__ chist) {
  __shared__ int lh[NB];
  int t = threadIdx.x;
  for (int i = t; i < NB; i += 256) lh[i] = 0;
  __syncthreads();
  int e0 = blockIdx.x * EPB;
#pragma unroll
  for (int i = 0; i < EPB / 256; ++i) {
    int e = e0 + i * 256 + t;
    if (e < NE) atomicAdd(&lh[dst[e] >> 8], 1);
  }
  __syncthreads();
  for (int i = t; i < NB; i += 256)
    if (lh[i]) atomicAdd(&chist[i], lh[i]);
}

__global__ __launch_bounds__(256) void k_cscan(const int* __restrict__ chist,
                                               int* __restrict__ cbase,
                                               int* __restrict__ ccur) {
  __shared__ int ls[256];
  int t = threadIdx.x;
  int v = (t < NB) ? chist[t] : 0;
  ls[t] = v;
  __syncthreads();
  for (int off = 1; off < 256; off <<= 1) {
    int u = (t >= off) ? ls[t - off] : 0;
    __syncthreads();
    ls[t] += u;
    __syncthreads();
  }
  if (t < NB) { cbase[t] = ls[t] - v; ccur[t] = ls[t] - v; }
  if (t == 0) cbase[NB] = NE;
}

// -------- phase 1: partition packed records by coarse bucket --------

__global__ __launch_bounds__(256) void k_part(const int* __restrict__ src,
                                              const int* __restrict__ dst,
                                              int* __restrict__ ccur,
                                              int* __restrict__ pairs) {
  __shared__ int lh[NB];
  __shared__ int gb[NB];
  __shared__ int lc[NB];
  __shared__ int ls[256];
  __shared__ int lp[EPB];
  __shared__ int gx[EPB];
  int t = threadIdx.x;
  for (int i = t; i < NB; i += 256) lh[i] = 0;
  __syncthreads();
  int e0 = blockIdx.x * EPB;
  int nloc = NE - e0; if (nloc > EPB) nloc = EPB;
#pragma unroll
  for (int i = 0; i < EPB / 256; ++i) {
    int e = e0 + i * 256 + t;
    if (e < NE) atomicAdd(&lh[dst[e] >> 8], 1);
  }
  __syncthreads();
  int v = (t < NB) ? lh[t] : 0;
  ls[t] = v;
  __syncthreads();
  for (int off = 1; off < 256; off <<= 1) {
    int u = (t >= off) ? ls[t - off] : 0;
    __syncthreads();
    ls[t] += u;
    __syncthreads();
  }
  int lbase = ls[t] - v;
  int gbase = 0;
  if (t < NB && v > 0) gbase = atomicAdd(&ccur[t], v);
  if (t < NB) { lh[t] = lbase; gb[t] = gbase; lc[t] = 0; }
  __syncthreads();
#pragma unroll
  for (int i = 0; i < EPB / 256; ++i) {
    int e = e0 + i * 256 + t;
    if (e < NE) {
      int d = dst[e], s = src[e];
      int b = d >> 8;
      int lpos = lh[b] + atomicAdd(&lc[b], 1);
      lp[lpos] = ((d & 255) << 16) | s;
      gx[lpos] = gb[b] - lh[b];
    }
  }
  __syncthreads();
  for (int i = t; i < nloc; i += 256) pairs[gx[i] + i] = lp[i];
}

// ---------------- phase 2: exact sort within bucket ----------------

__global__ __launch_bounds__(256) void k_sub(const int* __restrict__ pairs,
                                             const int* __restrict__ cbase,
                                             int* __restrict__ rowptr,
                                             int* __restrict__ ebuf) {
  __shared__ int lh[256];
  __shared__ int lsc[256];
  __shared__ int lc2[256];
  __shared__ unsigned short ssrc[CAP];
  int t = threadIdx.x;
  int b = blockIdx.x;
  int beg = cbase[b], end = cbase[b + 1];
  int n = end - beg;
  lh[t] = 0;
  lc2[t] = 0;
  __syncthreads();
  for (int i = t; i < n; i += 256) atomicAdd(&lh[(pairs[beg + i] >> 16) & 255], 1);
  __syncthreads();
  int v = lh[t];
  lsc[t] = v;
  __syncthreads();
  for (int off = 1; off < 256; off <<= 1) {
    int u = (t >= off) ? lsc[t - off] : 0;
    __syncthreads();
    lsc[t] += u;
    __syncthreads();
  }
  int excl = lsc[t] - v;
  int node = b * 256 + t;
  if (node <= NN) rowptr[node] = beg + excl;
  for (int i = t; i < n; i += 256) {
    int p = pairs[beg + i];
    int ln = (p >> 16) & 255;
    int lpos = (lsc[ln] - lh[ln]) + atomicAdd(&lc2[ln], 1);
    if (lpos < CAP) ssrc[lpos] = (unsigned short)(p & 0xFFFF);
  }
  __syncthreads();
  for (int i = t; i < n; i += 256) ebuf[beg + i] = (int)ssrc[i];
}

// ------ aggregation (bf16 gather, 4 edges/wave-iter) with fused BN affine:
// m[i] = scale .* (z[i] + sum_j zb[j]) + (deg_i + 1) * shift ------

__global__ __launch_bounds__(256) void k_agg(const float* __restrict__ z,
                                             const unsigned short* __restrict__ zb,
                                             const int* __restrict__ rowptr,
                                             const int* __restrict__ ebuf,
                                             const float* __restrict__ part,
                                             const float* __restrict__ gamma,
                                             const float* __restrict__ beta,
                                             float* __restrict__ m) {
  __shared__ float sc[64], sh[64];
  int t = threadIdx.x;
  if (t < 64) {
    float s = 0.f, ss = 0.f;
#pragma unroll
    for (int c = 0; c < NCOPY; ++c) { s += part[c * 128 + t]; ss += part[c * 128 + 64 + t]; }
    float invn = 1.f / (float)NN;
    float mu = s * invn;
    float var = fmaxf(ss * invn - mu * mu, 0.f);
    float inv = rsqrtf(var + BN_EPS);
    float scale = gamma[t] * inv;
    sc[t] = scale;
    sh[t] = beta[t] - mu * scale;
  }
  __syncthreads();
  int lane = t & 63;
  int node = blockIdx.x * 4 + (t >> 6);
  int slot = lane >> 4;   // edge slot 0..3
  int cg = lane & 15;     // channel group: channels 4cg..4cg+3
  int beg = rowptr[node], end = rowptr[node + 1];
  float a0 = 0.f, a1 = 0.f, a2 = 0.f, a3 = 0.f;
  // self term in fp32 (slot 0 only)
  if (slot == 0) {
    float4 sv = ((const float4*)(z + (size_t)node * NH))[cg];
    a0 = sv.x; a1 = sv.y; a2 = sv.z; a3 = sv.w;
  }
  int j = beg + slot;
  for (; j + 4 < end; j += 8) {
    int s0 = ebuf[j];
    int s1 = ebuf[j + 4];
    uint2 u0 = *(const uint2*)(zb + (size_t)s0 * NH + cg * 4);
    uint2 u1 = *(const uint2*)(zb + (size_t)s1 * NH + cg * 4);
    a0 += bf_lo_f(u0.x) + bf_lo_f(u1.x);
    a1 += bf_hi_f(u0.x) + bf_hi_f(u1.x);
    a2 += bf_lo_f(u0.y) + bf_lo_f(u1.y);
    a3 += bf_hi_f(u0.y) + bf_hi_f(u1.y);
  }
  for (; j < end; j += 4) {
    int s0 = ebuf[j];
    uint2 u0 = *(const uint2*)(zb + (size_t)s0 * NH + cg * 4);
    a0 += bf_lo_f(u0.x);
    a1 += bf_hi_f(u0.x);
    a2 += bf_lo_f(u0.y);
    a3 += bf_hi_f(u0.y);
  }
  a0 += __shfl_xor(a0, 16); a0 += __shfl_xor(a0, 32);
  a1 += __shfl_xor(a1, 16); a1 += __shfl_xor(a1, 32);
  a2 += __shfl_xor(a2, 16); a2 += __shfl_xor(a2, 32);
  a3 += __shfl_xor(a3, 16); a3 += __shfl_xor(a3, 32);
  if (slot == 0) {
    float deg1 = (float)(end - beg + 1);
    int c0 = cg * 4;
    float4 o;
    o.x = sc[c0 + 0] * a0 + deg1 * sh[c0 + 0];
    o.y = sc[c0 + 1] * a1 + deg1 * sh[c0 + 1];
    o.z = sc[c0 + 2] * a2 + deg1 * sh[c0 + 2];
    o.w = sc[c0 + 3] * a3 + deg1 * sh[c0 + 3];
    ((float4*)(m + (size_t)node * NH))[cg] = o;
  }
}

// ---------------- input transform (MFMA): z = x @ Wt + bt (+bf16 plane, stats) ----------------

__global__ __launch_bounds__(256) void k_in(const float* __restrict__ x,
                                            const float* __restrict__ Wt,
                                            const float* __restrict__ bt,
                                            float* __restrict__ z,
                                            unsigned short* __restrict__ zb,
                                            float* __restrict__ part_out) {
  __shared__ unsigned short wh[8192], wl[8192];  // 32 KB
  __shared__ float reds[16][64], redss[16][64];  // 8 KB
  int t = threadIdx.x;
  stage_w<NF>(Wt, wh, wl);
  int wv = t >> 6, lane = t & 63;
  int c15 = lane & 15, kg = lane >> 4;
  int n0 = blockIdx.x * 64 + wv * 16;
  int arow = n0 + c15;

  bf16x8 ah[4], al[4];
  const float* ap = x + (size_t)arow * NF + kg * 8;
#pragma unroll
  for (int ks = 0; ks < 4; ++ks) make_ab(ap + ks * 32, arow < NN, ah[ks], al[ks]);
  __syncthreads();

  const bf16x8* bh = (const bf16x8*)wh;
  const bf16x8* bl = (const bf16x8*)wl;
  float sAcc[4], ssAcc[4];
#pragma unroll
  for (int ct = 0; ct < 4; ++ct) {
    f32x4 acc = {0.f, 0.f, 0.f, 0.f};
#pragma unroll
    for (int ks = 0; ks < 4; ++ks) {
      bf16x8 wbh = bh[(ks * 4 + ct) * 64 + kg * 16 + c15];
      bf16x8 wbl = bl[(ks * 4 + ct) * 64 + kg * 16 + c15];
      acc = MFMA(al[ks], wbh, acc, 0, 0, 0);
      acc = MFMA(ah[ks], wbl, acc, 0, 0, 0);
      acc = MFMA(ah[ks], wbh, acc, 0, 0, 0);
    }
    float b = bt[ct * 16 + c15];
    float s = 0.f, ss = 0.f;
#pragma unroll
    for (int g = 0; g < 4; ++g) {
      int row = n0 + kg * 4 + g;
      float v = acc[g] + b;
      if (row < NN) {
        z[(size_t)row * NH + ct * 16 + c15] = v;
        zb[(size_t)row * NH + ct * 16 + c15] = bf_hi(v);
        s += v;
        ss += v * v;
      }
    }
    sAcc[ct] = s;
    ssAcc[ct] = ss;
  }
#pragma unroll
  for (int ct = 0; ct < 4; ++ct) {
    reds[wv * 4 + kg][ct * 16 + c15] = sAcc[ct];
    redss[wv * 4 + kg][ct * 16 + c15] = ssAcc[ct];
  }
  __syncthreads();
  if (t < 64) {
    float s2 = 0.f, ss2 = 0.f;
#pragma unroll
    for (int i = 0; i < 16; ++i) { s2 += reds[i][t]; ss2 += redss[i][t]; }
    int cp = (blockIdx.x & (NCOPY - 1)) * 128;
    atomicAdd(&part_out[cp + t], s2);
    atomicAdd(&part_out[cp + 64 + t], ss2);
  }
}

// ---------------- MLP (MFMA): r = relu(relu(m@W1)@W2) (+bf16 plane, stats) ----------------

__global__ __launch_bounds__(256) void k_mlp(const float* __restrict__ m,
                                             const float* __restrict__ W1,
                                             const float* __restrict__ W2,
                                             float* __restrict__ r,
                                             unsigned short* __restrict__ rb,
                                             float* __restrict__ part_out) {
  __shared__ unsigned short w1h[4096], w1l[4096], w2h[4096], w2l[4096];  // 32 KB
  __shared__ unsigned short tls[4][2][16][72];                           // 18.4 KB
  __shared__ float reds[16][64], redss[16][64];                          // 8 KB
  int t = threadIdx.x;
  stage_w<NH>(W1, w1h, w1l);
  stage_w<NH>(W2, w2h, w2l);
  int wv = t >> 6, lane = t & 63;
  int c15 = lane & 15, kg = lane >> 4;
  int n0 = blockIdx.x * 64 + wv * 16;
  int arow = n0 + c15;

  bf16x8 ah[2], al[2];
  const float* ap = m + (size_t)arow * NH + kg * 8;
  make_ab(ap, arow < NN, ah[0], al[0]);
  make_ab(ap + 32, arow < NN, ah[1], al[1]);
  __syncthreads();

  const bf16x8* b1h = (const bf16x8*)w1h;
  const bf16x8* b1l = (const bf16x8*)w1l;
  float tv[4][4];
#pragma unroll
  for (int ct = 0; ct < 4; ++ct) {
    f32x4 acc = {0.f, 0.f, 0.f, 0.f};
#pragma unroll
    for (int ks = 0; ks < 2; ++ks) {
      bf16x8 wbh = b1h[(ks * 4 + ct) * 64 + kg * 16 + c15];
      bf16x8 wbl = b1l[(ks * 4 + ct) * 64 + kg * 16 + c15];
      acc = MFMA(al[ks], wbh, acc, 0, 0, 0);
      acc = MFMA(ah[ks], wbl, acc, 0, 0, 0);
      acc = MFMA(ah[ks], wbh, acc, 0, 0, 0);
    }
#pragma unroll
    for (int g = 0; g < 4; ++g) tv[ct][g] = fmaxf(acc[g], 0.f);
  }
#pragma unroll
  for (int ct = 0; ct < 4; ++ct)
#pragma unroll
    for (int g = 0; g < 4; ++g) {
      int rr = kg * 4 + g, cc = ct * 16 + c15;
      unsigned short h = bf_hi(tv[ct][g]);
      tls[wv][0][rr][cc] = h;
      tls[wv][1][rr][cc] = bf_hi(tv[ct][g] - bf_to_f(h));
    }
  __syncthreads();

  bf16x8 a2h[2], a2l[2];
#pragma unroll
  for (int ks = 0; ks < 2; ++ks) {
    a2h[ks] = *(const bf16x8*)&tls[wv][0][c15][ks * 32 + kg * 8];
    a2l[ks] = *(const bf16x8*)&tls[wv][1][c15][ks * 32 + kg * 8];
  }
  const bf16x8* b2h = (const bf16x8*)w2h;
  const bf16x8* b2l = (const bf16x8*)w2l;
  float sAcc[4], ssAcc[4];
#pragma unroll
  for (int ct = 0; ct < 4; ++ct) {
    f32x4 acc = {0.f, 0.f, 0.f, 0.f};
#pragma unroll
    for (int ks = 0; ks < 2; ++ks) {
      bf16x8 wbh = b2h[(ks * 4 + ct) * 64 + kg * 16 + c15];
      bf16x8 wbl = b2l[(ks * 4 + ct) * 64 + kg * 16 + c15];
      acc = MFMA(a2l[ks], wbh, acc, 0, 0, 0);
      acc = MFMA(a2h[ks], wbl, acc, 0, 0, 0);
      acc = MFMA(a2h[ks], wbh, acc, 0, 0, 0);
    }
    float s = 0.f, ss = 0.f;
#pragma unroll
    for (int g = 0; g < 4; ++g) {
      float v = fmaxf(acc[g], 0.f);
      int row = n0 + kg * 4 + g;
      if (row < NN) {
        r[(size_t)row * NH + ct * 16 + c15] = v;
        rb[(size_t)row * NH + ct * 16 + c15] = bf_hi(v);
      }
      s += v;
      ss += v * v;
    }
    sAcc[ct] = s;
    ssAcc[ct] = ss;
  }
#pragma unroll
  for (int ct = 0; ct < 4; ++ct) {
    reds[wv * 4 + kg][ct * 16 + c15] = sAcc[ct];
    redss[wv * 4 + kg][ct * 16 + c15] = ssAcc[ct];
  }
  __syncthreads();
  if (t < 64) {
    float s2 = 0.f, ss2 = 0.f;
#pragma unroll
    for (int i = 0; i < 16; ++i) { s2 += reds[i][t]; ss2 += redss[i][t]; }
    int cp = (blockIdx.x & (NCOPY - 1)) * 128;
    atomicAdd(&part_out[cp + t], s2);
    atomicAdd(&part_out[cp + 64 + t], ss2);
  }
}

// ---------------- final BN apply ----------------

__global__ __launch_bounds__(256) void k_apply(const float* __restrict__ r,
                                               const float* __restrict__ part,
                                               const float* __restrict__ gamma,
                                               const float* __restrict__ beta,
                                               float* __restrict__ out) {
  __shared__ float sc[64], sh[64];
  int t = threadIdx.x;
  if (t < 64) {
    float s = 0.f, ss = 0.f;
#pragma unroll
    for (int c = 0; c < NCOPY; ++c) { s += part[c * 128 + t]; ss += part[c * 128 + 64 + t]; }
    float invn = 1.f / (float)NN;
    float mu = s * invn;
    float var = fmaxf(ss * invn - mu * mu, 0.f);
    float inv = rsqrtf(var + BN_EPS);
    float scale = gamma[t] * inv;
    sc[t] = scale;
    sh[t] = beta[t] - mu * scale;
  }
  __syncthreads();
  int i = blockIdx.x * 256 + t;  // float4 index
  if (i < NN * (NH / 4)) {
    int c0 = (i * 4) & 63;
    float4 v = ((const float4*)r)[i];
    float4 o;
    o.x = v.x * sc[c0 + 0] + sh[c0 + 0];
    o.y = v.y * sc[c0 + 1] + sh[c0 + 1];
    o.z = v.z * sc[c0 + 2] + sh[c0 + 2];
    o.w = v.w * sc[c0 + 3] + sh[c0 + 3];
    ((float4*)out)[i] = o;
  }
}

// ---------------- launch ----------------

extern "C" void kernel_launch(void* const* d_in, const int* in_sizes, int n_in,
                              void* d_out, int out_size, void* d_ws, size_t ws_size,
                              hipStream_t stream) {
  (void)in_sizes; (void)n_in; (void)out_size; (void)ws_size;
  const float* x      = (const float*)d_in[0];
  const int*   ei     = (const int*)d_in[1];
  const float* Wt     = (const float*)d_in[2];
  const float* bt     = (const float*)d_in[3];
  const float* gt     = (const float*)d_in[4];
  const float* bet    = (const float*)d_in[5];
  const float* Ws1    = (const float*)d_in[6];
  const float* Ws2    = (const float*)d_in[7];
  const float* gammas = (const float*)d_in[8];
  const float* betas  = (const float*)d_in[9];

  const int* esrc = ei;
  const int* edst = ei + NE;

  float*          bufA     = (float*)d_ws;                     // 3.2M floats (pairs aliased)
  float*          bufB     = bufA + (size_t)NN * NH;           // 3.2M floats
  int*            ebuf     = (int*)(bufB + (size_t)NN * NH);   // NE
  int*            rowptr   = ebuf + NE;                        // NN+1
  int*            chist    = rowptr + NN + 1;                  // NB
  int*            cbase    = chist + NB;                       // NB+1
  int*            ccur     = cbase + NB + 1;                   // NB
  float*          partials = (float*)(ccur + NB);              // 4 x SEG
  unsigned short* bfA      = (unsigned short*)(partials + 4 * SEG);  // NN*NH bf16
  unsigned short* bfB      = bfA + (size_t)NN * NH;                  // NN*NH bf16
  int*            pairs    = (int*)bufA;                       // NE ints, dead before k_in

  const int GB = (NN + 63) / 64;  // 782

  // CSR build (two-phase bucketed sort by dst, packed records)
  k_zero<<<(4 * SEG + 255) / 256, 256, 0, stream>>>(chist, partials);
  k_hist<<<(NE + EPB - 1) / EPB, 256, 0, stream>>>(edst, chist);
  k_cscan<<<1, 256, 0, stream>>>(chist, cbase, ccur);
  k_part<<<(NE + EPB - 1) / EPB, 256, 0, stream>>>(esrc, edst, ccur, pairs);
  k_sub<<<NB, 256, 0, stream>>>(pairs, cbase, rowptr, ebuf);

  // input transform (z fp32 + bf16 plane + stats seg0)
  k_in<<<GB, 256, 0, stream>>>(x, Wt, bt, bufA, bfA, partials);

  // L0
  k_agg<<<NN / 4, 256, 0, stream>>>(bufA, bfA, rowptr, ebuf, partials, gt, bet, bufB);
  k_mlp<<<GB, 256, 0, stream>>>(bufB, Ws1, Ws2, bufB, bfB, partials + SEG);

  // L1
  k_agg<<<NN / 4, 256, 0, stream>>>(bufB, bfB, rowptr, ebuf, partials + SEG, gammas, betas,
                                    bufA);
  k_mlp<<<GB, 256, 0, stream>>>(bufA, Ws1 + NH * NH, Ws2 + NH * NH, bufA, bfA,
                                partials + 2 * SEG);

  // L2
  k_agg<<<NN / 4, 256, 0, stream>>>(bufA, bfA, rowptr, ebuf, partials + 2 * SEG, gammas + NH,
                                    betas + NH, bufB);
  k_mlp<<<GB, 256, 0, stream>>>(bufB, Ws1 + 2 * NH * NH, Ws2 + 2 * NH * NH, bufB, bfB,
                                partials + 3 * SEG);

  // final BN apply -> d_out
  k_apply<<<(NN * (NH / 4) + 255) / 256, 256, 0, stream>>>(bufB, partials + 3 * SEG,
                                                           gammas + 2 * NH, betas + 2 * NH,
                                                           (float*)d_out);
}